// Round 7
// baseline (594.978 us; speedup 1.0000x reference)
//
#include <hip/hip_runtime.h>

#define NN 128
#define NITER 300
#define NROUND 4   // 4 rounds x 4-point bracket (/625) + 2 exact Newton steps —
                   // proven config. FIXED path (R4 lesson), no hot-loop LDS
                   // (R5 lesson), single-broadcast reductions (R6, kept), NO
                   // block-prefetch movs (R6 regression, dropped).

typedef _Float16 h2 __attribute__((ext_vector_type(2)));

#if __has_builtin(__builtin_amdgcn_fdot2)
  #define FDOT2(a, b, c) __builtin_amdgcn_fdot2((a), (b), (c), false)
#else   // compile-safe fallback (slower): unpack + 2 fma
  #define FDOT2(a, b, c) fmaf((float)(a).x, (float)(b).x, \
                         fmaf((float)(a).y, (float)(b).y, (c)))
#endif

__device__ __forceinline__ int h2_to_i(h2 v) { union { h2 h; int i; } u; u.h = v; return u.i; }
__device__ __forceinline__ h2  i_to_h2(int x) { union { h2 h; int i; } u; u.i = x; return u.h; }

// ---- DPP wave-64 cross-lane helpers ----
template<int CTRL>
__device__ __forceinline__ float dpp0(float x) {  // invalid lanes contribute 0
  return __int_as_float(__builtin_amdgcn_update_dpp(0, __float_as_int(x), CTRL, 0xF, 0xF, true));
}
template<int CTRL>
__device__ __forceinline__ float dppS(float x) {  // invalid lanes keep self
  int xi = __float_as_int(x);
  return __int_as_float(__builtin_amdgcn_update_dpp(xi, xi, CTRL, 0xF, 0xF, false));
}
__device__ __forceinline__ float bcast63(float x) {
  return __int_as_float(__builtin_amdgcn_readlane(__float_as_int(x), 63));
}
__device__ __forceinline__ float rlane(float x, int l) {   // l literal after unroll
  return __int_as_float(__builtin_amdgcn_readlane(__float_as_int(x), l));
}
__device__ __forceinline__ int rlanei(int x, int l) {
  return __builtin_amdgcn_readlane(x, l);
}
__device__ __forceinline__ float wsum(float x) {
  x += dpp0<0x111>(x); x += dpp0<0x112>(x); x += dpp0<0x114>(x);
  x += dpp0<0x118>(x); x += dpp0<0x142>(x); x += dpp0<0x143>(x);
  return bcast63(x);
}
// 4 interleaved chains; cnt computed on lane63's totals, ONE bcast63 (R6)
__device__ __forceinline__ float wsum4_cnt(float a, float b, float c, float d) {
  a += dpp0<0x111>(a); b += dpp0<0x111>(b); c += dpp0<0x111>(c); d += dpp0<0x111>(d);
  a += dpp0<0x112>(a); b += dpp0<0x112>(b); c += dpp0<0x112>(c); d += dpp0<0x112>(d);
  a += dpp0<0x114>(a); b += dpp0<0x114>(b); c += dpp0<0x114>(c); d += dpp0<0x114>(d);
  a += dpp0<0x118>(a); b += dpp0<0x118>(b); c += dpp0<0x118>(c); d += dpp0<0x118>(d);
  a += dpp0<0x142>(a); b += dpp0<0x142>(b); c += dpp0<0x142>(c); d += dpp0<0x142>(d);
  a += dpp0<0x143>(a); b += dpp0<0x143>(b); c += dpp0<0x143>(c); d += dpp0<0x143>(d);
  float cnt = ((a > 1.f ? 1.f : 0.f) + (b > 1.f ? 1.f : 0.f))
            + ((c > 1.f ? 1.f : 0.f) + (d > 1.f ? 1.f : 0.f));
  return bcast63(cnt);
}
// 2 interleaved chains; tau computed on lane63's totals, ONE bcast63 (R6)
__device__ __forceinline__ float wsum2_tau(float sfv, float cnt) {
  float a = sfv, b = cnt;
  a += dpp0<0x111>(a); b += dpp0<0x111>(b);
  a += dpp0<0x112>(a); b += dpp0<0x112>(b);
  a += dpp0<0x114>(a); b += dpp0<0x114>(b);
  a += dpp0<0x118>(a); b += dpp0<0x118>(b);
  a += dpp0<0x142>(a); b += dpp0<0x142>(b);
  a += dpp0<0x143>(a); b += dpp0<0x143>(b);
  float nu    = floorf(b * (1.f / 1024.f));
  float nfree = fmaxf(b - 1024.f * nu, 1.f);
  float tau   = (a + nu - 1.f) * __builtin_amdgcn_rcpf(nfree);
  return bcast63(tau);
}
__device__ __forceinline__ void wminmax(float& mn, float& mx) {  // interleaved
  mn = fminf(mn, dppS<0x111>(mn)); mx = fmaxf(mx, dppS<0x111>(mx));
  mn = fminf(mn, dppS<0x112>(mn)); mx = fmaxf(mx, dppS<0x112>(mx));
  mn = fminf(mn, dppS<0x114>(mn)); mx = fmaxf(mx, dppS<0x114>(mx));
  mn = fminf(mn, dppS<0x118>(mn)); mx = fmaxf(mx, dppS<0x118>(mx));
  mn = fminf(mn, dppS<0x142>(mn)); mx = fmaxf(mx, dppS<0x142>(mx));
  mn = fminf(mn, dppS<0x143>(mn)); mx = fmaxf(mx, dppS<0x143>(mx));
  mn = bcast63(mn); mx = bcast63(mx);
}

// ONE WAVE PER SAMPLE at TWO WAVES/SIMD (the R7 occupancy play):
//   Q compressed to f16, packed pairs qX[u] = {Q[r][u], Q[r][u+64]} -> 128
//   dwords/lane total -> fits the 256-reg budget of __launch_bounds__(64,2).
//   Matvec = 128 v_dot2_f32_f16 + 64 readlanes (y packed f16 pair/lane).
//   Build runs in TWO half-row passes (peak regs ~222) re-reading cov.
//   The co-resident wave fills this wave's DPP-chain stalls.
__launch_bounds__(64, 2)
__global__ void markowitz_kernel(const float* __restrict__ rets,
                                 const float* __restrict__ cov,
                                 const float* __restrict__ gam,
                                 const float* __restrict__ alp,
                                 float* __restrict__ out)
{
  const int b    = blockIdx.x;
  const int lane = threadIdx.x;          // block = exactly one wave (64)

  const float g   = gam[b];
  const float g2  = g * g;
  const float aab = fabsf(alp[b]);
  const float* cb = cov + (size_t)b * (NN * NN);
  const float* ap0 = cb + lane;
  const float* ap1 = cb + lane + 64;

  h2 qA[64], qB[64];        // packed rows lane / lane+64 (unscaled g2*CtC+aI)
  float qdA = 0.f, qdB = 0.f;  // f16-stored diagonal values (f32), for y-quant fix
  float ssA, ssB;           // Frobenius partials

  // ---------- pass A: row `lane` ----------
  {
    float acc[NN];
    #pragma unroll
    for (int u = 0; u < NN; ++u) acc[u] = 0.f;
    #pragma unroll 2
    for (int k = 0; k < NN; ++k) {
      float a0 = ap0[(size_t)k * NN];    // C[k][lane]  (row multiplier)
      float a1 = ap1[(size_t)k * NN];    // C[k][lane+64] (broadcast source)
      #pragma unroll
      for (int u = 0; u < 64; ++u) {
        float s0 = rlane(a0, u);         // C[k][u]
        float s1 = rlane(a1, u);         // C[k][64+u]
        acc[u]      = fmaf(a0, s0, acc[u]);
        acc[64 + u] = fmaf(a0, s1, acc[64 + u]);
      }
    }
    float s0 = 0.f, s1 = 0.f;
    #pragma unroll
    for (int u = 0; u < 64; ++u) {
      float qa = g2 * acc[u];      if (u == lane) qa += aab;  // diag col=lane
      float qb = g2 * acc[u + 64];
      s0 = fmaf(qa, qa, s0); s1 = fmaf(qb, qb, s1);
      h2 p; p.x = (_Float16)qa; p.y = (_Float16)qb;
      qA[u] = p;
      if (u == lane) qdA = (float)p.x;
    }
    ssA = s0 + s1;
  }

  // ---------- pass B: row `lane+64` ----------
  {
    float acc[NN];
    #pragma unroll
    for (int u = 0; u < NN; ++u) acc[u] = 0.f;
    #pragma unroll 2
    for (int k = 0; k < NN; ++k) {
      float a0 = ap0[(size_t)k * NN];
      float a1 = ap1[(size_t)k * NN];    // row multiplier for row lane+64
      #pragma unroll
      for (int u = 0; u < 64; ++u) {
        float s0 = rlane(a0, u);
        float s1 = rlane(a1, u);
        acc[u]      = fmaf(a1, s0, acc[u]);
        acc[64 + u] = fmaf(a1, s1, acc[64 + u]);
      }
    }
    float s0 = 0.f, s1 = 0.f;
    #pragma unroll
    for (int u = 0; u < 64; ++u) {
      float qa = g2 * acc[u];
      float qb = g2 * acc[u + 64]; if (u == lane) qb += aab;  // diag col=lane+64
      s0 = fmaf(qa, qa, s0); s1 = fmaf(qb, qb, s1);
      h2 p; p.x = (_Float16)qa; p.y = (_Float16)qb;
      qB[u] = p;
      if (u == lane) qdB = (float)p.y;
    }
    ssB = s0 + s1;
  }

  const float S    = wsum(ssA + ssB);    // ||Q||_F^2 (f32, pre-rounding)
  const float step = 0.5f / sqrtf(S);    // 1/(2||Q||_F)
  const float sc   = 2.f * step;         // matvec is UNSCALED; scale applied to p

  const float r2a = step * rets[b * NN + lane];
  const float r2b = step * rets[b * NN + 64 + lane];

  // ---------- FISTA, fully in-wave ----------
  float y0 = 1.f / 128.f, y1 = 1.f / 128.f;   // y coords (lane, lane+64)
  float w0p = y0, w1p = y1;                   // w_prev
  float t_f = 1.f;

  #pragma unroll 1
  for (int it = 0; it < NITER; ++it) {
    // momentum scalars hoisted (latency hides under matvec)
    float tn   = 0.5f * (1.f + sqrtf(1.f + 4.f * t_f * t_f));
    float coef = (t_f - 1.f) * __builtin_amdgcn_rcpf(tn);

    // pack y into one f16 pair per lane; keep quantization residuals
    h2 yp; yp.x = (_Float16)y0; yp.y = (_Float16)y1;
    const int ypi = h2_to_i(yp);
    float dy0 = y0 - (float)yp.x;
    float dy1 = y1 - (float)yp.y;

    // matvec: 64 readlane (packed pair) + 128 dot2, 2 chains per row
    float pA0 = 0.f, pA1 = 0.f, pB0 = 0.f, pB1 = 0.f;
    #pragma unroll
    for (int u = 0; u < 64; u += 2) {
      h2 yv0 = i_to_h2(rlanei(ypi, u));
      h2 yv1 = i_to_h2(rlanei(ypi, u + 1));
      pA0 = FDOT2(qA[u],     yv0, pA0);
      pB0 = FDOT2(qB[u],     yv0, pB0);
      pA1 = FDOT2(qA[u + 1], yv1, pA1);
      pB1 = FDOT2(qB[u + 1], yv1, pB1);
    }
    // diagonal correction for y-quantization (largest single term)
    float p0 = (pA0 + pA1) + qdA * dy0;
    float p1 = (pB0 + pB1) + qdB * dy1;
    float v0 = (y0 + r2a) - sc * p0;     // v = y - step*grad
    float v1 = (y1 + r2b) - sc * p1;

    // projection onto {sum w=1, 0<=w<=1}: 4 rounds x 4-point bracket search
    float mn = fminf(v0, v1), mx = fmaxf(v0, v1);
    wminmax(mn, mx);
    float lo = mn - 1.0f;
    float W  = mx - lo;
    #pragma unroll 1
    for (int r = 0; r < NROUND; ++r) {
      float h  = W * 0.2f;
      float t1v = lo + h, t2v = lo + 2.f*h, t3v = lo + 3.f*h, t4v = lo + 4.f*h;
      float sa = __builtin_amdgcn_fmed3f(v0 - t1v, 0.f, 1.f)
               + __builtin_amdgcn_fmed3f(v1 - t1v, 0.f, 1.f);
      float sb = __builtin_amdgcn_fmed3f(v0 - t2v, 0.f, 1.f)
               + __builtin_amdgcn_fmed3f(v1 - t2v, 0.f, 1.f);
      float sc4 = __builtin_amdgcn_fmed3f(v0 - t3v, 0.f, 1.f)
               + __builtin_amdgcn_fmed3f(v1 - t3v, 0.f, 1.f);
      float sd = __builtin_amdgcn_fmed3f(v0 - t4v, 0.f, 1.f)
               + __builtin_amdgcn_fmed3f(v1 - t4v, 0.f, 1.f);
      float cnt = wsum4_cnt(sa, sb, sc4, sd);   // ONE broadcast per round
      lo = fmaf(cnt, h, lo);
      W  = h;
    }
    float tauf = lo + 0.5f * W;

    // two exact active-set Newton steps; second also produces w
    float w0 = 0.f, w1 = 0.f;
    #pragma unroll
    for (int e = 0; e < 2; ++e) {
      float z0 = v0 - tauf, z1 = v1 - tauf;
      bool fr0 = (z0 > 0.f) && (z0 < 1.0f);
      bool fr1 = (z1 > 0.f) && (z1 < 1.0f);
      bool cp0 = (z0 >= 1.0f), cp1 = (z1 >= 1.0f);
      float sfv = (fr0 ? v0 : 0.f) + (fr1 ? v1 : 0.f);
      float cnt = (fr0 ? 1.f : 0.f) + (fr1 ? 1.f : 0.f)
                + 1024.f * ((cp0 ? 1.f : 0.f) + (cp1 ? 1.f : 0.f));
      tauf = wsum2_tau(sfv, cnt);               // ONE broadcast per step
      if (e == 1) {
        w0 = fr0 ? (v0 - tauf) : (cp0 ? 1.0f : 0.f);
        w1 = fr1 ? (v1 - tauf) : (cp1 ? 1.0f : 0.f);
      }
    }

    // FISTA momentum
    y0 = w0 + coef * (w0 - w0p);
    y1 = w1 + coef * (w1 - w1p);
    w0p = w0; w1p = w1;
    t_f = tn;
  }

  out[(size_t)b * NN + lane]      = w0p;
  out[(size_t)b * NN + 64 + lane] = w1p;
}

extern "C" void kernel_launch(void* const* d_in, const int* in_sizes, int n_in,
                              void* d_out, int out_size, void* d_ws, size_t ws_size,
                              hipStream_t stream) {
  (void)n_in; (void)d_ws; (void)ws_size; (void)out_size;
  const float* rets = (const float*)d_in[0];
  const float* cov  = (const float*)d_in[1];
  const float* gam  = (const float*)d_in[2];
  const float* alp  = (const float*)d_in[3];
  float* out = (float*)d_out;
  const int B = in_sizes[0] / NN;   // 1024 waves, one sample each, 2 waves/SIMD
  markowitz_kernel<<<B, 64, 0, stream>>>(rets, cov, gam, alp, out);
}